// Round 7
// baseline (315.714 us; speedup 1.0000x reference)
//
#include <hip/hip_runtime.h>
#include <stdint.h>

#define L2E 1.44269504088896f

static __device__ __forceinline__ float wsum(float v) {
    #pragma unroll
    for (int m = 1; m < 64; m <<= 1) v += __shfl_xor(v, m, 64);
    return v;
}
static __device__ __forceinline__ float sigm(float x) {
    return 1.0f / (1.0f + __builtin_amdgcn_exp2f(-x * L2E));
}
static __device__ __forceinline__ float tanh_(float x) {
    const float ax = fabsf(x);
    const float t = __builtin_amdgcn_exp2f(-2.0f * ax * L2E);
    const float r = (1.0f - t) / (1.0f + t);
    return (x < 0.f) ? -r : r;
}

// DPP helper: returns neighbor's value per compile-time ctrl (VALU-rate).
template <int CTRL>
static __device__ __forceinline__ float dppterm(float v) {
    return __int_as_float(__builtin_amdgcn_update_dpp(
        0, __float_as_int(v), CTRL, 0xF, 0xF, true));
}
// Butterfly sum over 8 contiguous lanes (chunk = lane&7). All adds
// commutative -> bitwise-identical result in all 8 lanes.
static __device__ __forceinline__ float red8(float v) {
    v += dppterm<0xB1>(v);    // quad_perm(1,0,3,2)  = xor1
    v += dppterm<0x4E>(v);    // quad_perm(2,3,0,1)  = xor2
    v += dppterm<0x141>(v);   // row_half_mirror     = xor7 (quads merged)
    return v;
}

// ---------------------------------------------------------------------------
// init: fused weight transpose (wihT/whhT/WkT) + slot broadcast + iter-0
// gkq/aux. grid 112 x 256. (R1-verbatim)
// ---------------------------------------------------------------------------
__global__ __launch_bounds__(256) void init_kernel(
    const float* __restrict__ s0,
    const float* __restrict__ lsg, const float* __restrict__ lsb,
    const float* __restrict__ Wq,  const float* __restrict__ Wk,
    const float* __restrict__ lig, const float* __restrict__ lib,
    const float* __restrict__ wih, const float* __restrict__ whh,
    float* __restrict__ slots, float* __restrict__ gkq, float* __restrict__ aux,
    float* __restrict__ wihT, float* __restrict__ whhT, float* __restrict__ WkT)
{
    __shared__ float wkT[4096];
    __shared__ float scr[4][64];
    const int tid = threadIdx.x, lane = tid & 63, wv = tid >> 6;
    const int idx = blockIdx.x * 256 + tid;

    if (idx < 12288) {
        const int i = idx / 192, j = idx - i * 192;
        wihT[idx] = wih[j * 64 + i];
    } else if (idx < 24576) {
        const int o = idx - 12288;
        const int i = o / 192, j = o - i * 192;
        whhT[o] = whh[j * 64 + i];
    } else {
        const int o = idx - 24576;
        const int p = o >> 6, d = o & 63;
        WkT[o] = Wk[d * 64 + p];
    }

    const int r = blockIdx.x * 4 + wv;          // 0..447
    const int s = r % 7;
    #pragma unroll
    for (int i = tid; i < 4096; i += 256) {
        const int d = i >> 6, p = i & 63;
        wkT[p * 64 + d] = Wk[i];
    }
    const float h = s0[s * 64 + lane];
    slots[r * 64 + lane] = h;
    __syncthreads();

    const float mean = wsum(h) * (1.0f / 64.0f);
    const float d = h - mean;
    const float var = wsum(d * d) * (1.0f / 64.0f);
    const float rs = rsqrtf(var + 1e-5f);
    const float sn = d * rs * lsg[lane] + lsb[lane];
    scr[wv][lane] = sn;
    __syncthreads();
    float q = 0.f;
    #pragma unroll 8
    for (int i = 0; i < 64; ++i) q = fmaf(scr[wv][i], Wq[i * 64 + lane], q);
    q *= 0.125f;
    __syncthreads();
    scr[wv][lane] = q;
    __syncthreads();
    float kq = 0.f;
    #pragma unroll 8
    for (int p = 0; p < 64; ++p) kq = fmaf(wkT[p * 64 + lane], scr[wv][p], kq);
    const float bk = wsum(lib[lane] * kq);
    const float gk = lig[lane] * kq;
    const float g1 = wsum(gk);
    gkq[r * 64 + lane] = gk;
    if (lane == 0) { aux[r * 2] = g1; aux[r * 2 + 1] = bk; }
}

// ---------------------------------------------------------------------------
// attn_first (iter 0): R1-verbatim attn + per-row LN stats store (m, rs are
// iteration-invariant; later iters load them). grid B*16 = 1024 x 256.
// ---------------------------------------------------------------------------
__global__ __launch_bounds__(256, 2) void attn_first(
    const float* __restrict__ x,
    const float* __restrict__ gkq, const float* __restrict__ aux,
    float* __restrict__ Ypart, float2* __restrict__ stats)
{
    __shared__ float ybuf[16][460];             // 29.4 KB
    const int tid = threadIdx.x, lane = tid & 63, wv = tid >> 6;
    const int b = blockIdx.x >> 4, chunk16 = blockIdx.x & 15;
    const int ck  = lane & 7;                   // dim-chunk 0..7
    const int rsl = lane >> 3;                  // row-slot 0..7

    float gk[7][8];
    {
        const float4* gp = (const float4*)(gkq + b * 448 + ck * 8);
        #pragma unroll
        for (int s = 0; s < 7; ++s) {
            const float4 u0 = gp[s * 16], u1 = gp[s * 16 + 1];
            gk[s][0] = u0.x; gk[s][1] = u0.y; gk[s][2] = u0.z; gk[s][3] = u0.w;
            gk[s][4] = u1.x; gk[s][5] = u1.y; gk[s][6] = u1.z; gk[s][7] = u1.w;
        }
    }
    const float* ab = aux + b * 14;
    float g1[7], bk[7];
    #pragma unroll
    for (int s = 0; s < 7; ++s) { g1[s] = ab[2 * s]; bk[s] = ab[2 * s + 1]; }

    float Yacc[7][8];
    #pragma unroll
    for (int s = 0; s < 7; ++s)
        #pragma unroll
        for (int j = 0; j < 8; ++j) Yacc[s][j] = 0.f;
    float cacc[7] = {0.f, 0.f, 0.f, 0.f, 0.f, 0.f, 0.f};

    const int rowbase = chunk16 * 256 + wv * 64 + rsl;     // within batch
    const float* rb = x + ((long)b * 4096 + rowbase) * 64 + ck * 8;
    float4 a0 = *(const float4*)(rb);
    float4 a1 = *(const float4*)(rb + 4);
    #pragma unroll 1
    for (int g = 0; g < 8; ++g) {
        const int gn = (g < 7) ? g + 1 : 7;
        const float4 n0 = *(const float4*)(rb + gn * 512);
        const float4 n1 = *(const float4*)(rb + gn * 512 + 4);

        const float xv[8] = {a0.x, a0.y, a0.z, a0.w, a1.x, a1.y, a1.z, a1.w};
        float sum = 0.f, ss = 0.f;
        #pragma unroll
        for (int j = 0; j < 8; ++j) { sum += xv[j]; ss = fmaf(xv[j], xv[j], ss); }
        float acc[7];
        #pragma unroll
        for (int s = 0; s < 7; ++s) {
            float a = 0.f;
            #pragma unroll
            for (int j = 0; j < 8; ++j) a = fmaf(xv[j], gk[s][j], a);
            acc[s] = a;
        }
        sum = red8(sum);
        ss  = red8(ss);
        #pragma unroll
        for (int s = 0; s < 7; ++s) acc[s] = red8(acc[s]);

        const float m   = sum * (1.0f / 64.0f);
        const float var = ss * (1.0f / 64.0f) - m * m;
        const float rs  = rsqrtf(var + 1e-5f);
        if (ck == 0)                             // 8 rows/wave/g, 64B coalesced
            stats[(long)b * 4096 + rowbase + g * 8] = make_float2(m, rs);
        const float rsm = rs * m;
        float t[7];
        #pragma unroll
        for (int s = 0; s < 7; ++s)
            t[s] = fmaf(rs, acc[s], fmaf(-rsm, g1[s], bk[s]));
        float mx = t[0];
        #pragma unroll
        for (int s = 1; s < 7; ++s) mx = fmaxf(mx, t[s]);
        float e[7], se = 0.f;
        #pragma unroll
        for (int s = 0; s < 7; ++s) {
            e[s] = __builtin_amdgcn_exp2f((t[s] - mx) * L2E);
            se += e[s];
        }
        const float inv = 1.0f / se;
        #pragma unroll
        for (int s = 0; s < 7; ++s) {
            const float w = fmaf(e[s], inv, 1e-8f);
            cacc[s] += w;
            const float wrs = w * rs;
            #pragma unroll
            for (int j = 0; j < 8; ++j)
                Yacc[s][j] = fmaf(wrs, xv[j], Yacc[s][j]);
        }
        a0 = n0; a1 = n1;
    }

    #pragma unroll
    for (int s = 0; s < 7; ++s) {
        #pragma unroll
        for (int j = 0; j < 8; ++j)
            Yacc[s][j] += dppterm<0x128>(Yacc[s][j]);
        cacc[s] += dppterm<0x128>(cacc[s]);
    }
    if (((lane >> 3) & 1) == 0) {
        const int sub = lane >> 4;
        float* yb = &ybuf[wv * 4 + sub][ck * 8];
        #pragma unroll
        for (int s = 0; s < 7; ++s) {
            #pragma unroll
            for (int j = 0; j < 8; ++j) yb[s * 64 + j] = Yacc[s][j];
        }
        if (ck == 0) {
            #pragma unroll
            for (int s = 0; s < 7; ++s)
                ybuf[wv * 4 + sub][448 + s] = cacc[s];
        }
    }
    __syncthreads();
    for (int i = tid; i < 455; i += 256) {
        float v = 0.f;
        #pragma unroll
        for (int p = 0; p < 16; ++p) v += ybuf[p][i];
        Ypart[((long)b * 16 + chunk16) * 456 + i] = v;
    }
}

// ---------------------------------------------------------------------------
// attn_fused (iters 1,2): PROLOGUE = redundant per-batch update_{i-1} (each
// of the 16 blocks of batch b computes the identical, bit-deterministic
// update; gkq/aux stay in LDS; slots stored redundantly-identically).
// Then R1-verbatim attn using LDS gkq/aux + preloaded LN stats. Ypart and
// slots double-buffered across dispatches (no intra-kernel cross-block
// communication). grid 1024 x 256.
// FIX vs R6: Ypart staging uses the 256-thread form (grid-stride + tid<7),
// R2/R4-verbatim. The R6 version used the 512-thread predicate form, so
// wsYd[4..6] and wsC were never written (absmax 5.26 failure).
// ---------------------------------------------------------------------------
__global__ __launch_bounds__(256, 2) void attn_fused(
    const float* __restrict__ x, const float2* __restrict__ stats,
    const float* __restrict__ Yprev, float* __restrict__ Ycur,
    const float* __restrict__ slots_rd, float* __restrict__ slots_wr,
    const float* __restrict__ Wv,
    const float* __restrict__ wihT, const float* __restrict__ whhT,
    const float* __restrict__ bih,  const float* __restrict__ bhh,
    const float* __restrict__ w1,   const float* __restrict__ b1,
    const float* __restrict__ w2,   const float* __restrict__ b2,
    const float* __restrict__ lsg,  const float* __restrict__ lsb,
    const float* __restrict__ Wq,   const float* __restrict__ WkT,
    const float* __restrict__ lig,  const float* __restrict__ lib)
{
    __shared__ float ybuf[16][460];             // 29.4 KB
    __shared__ float wsYd[7][64];
    __shared__ float wsC[8];
    __shared__ float wss[4][4][64];
    __shared__ float gkql[448];
    __shared__ float auxl[14];
    const int tid = threadIdx.x, lane = tid & 63, wv = tid >> 6;
    const int b = blockIdx.x >> 4, chunk16 = blockIdx.x & 15;
    const int ck  = lane & 7;
    const int rsl = lane >> 3;

    // early-issue first x tile + stats (completes under the prologue)
    const int rowbase = chunk16 * 256 + wv * 64 + rsl;
    const float* rb = x + ((long)b * 4096 + rowbase) * 64 + ck * 8;
    float4 a0 = *(const float4*)(rb);
    float4 a1 = *(const float4*)(rb + 4);
    float2 st = stats[(long)b * 4096 + rowbase];

    // ---- prologue: update_{i-1} for batch b (R2/R4-verbatim staging) ----
    const float* Yb = Yprev + (long)b * 16 * 456;
    for (int o = tid; o < 448; o += 256) {
        float v = 0.f;
        #pragma unroll
        for (int c = 0; c < 16; ++c) v += Yb[c * 456 + o];
        wsYd[o >> 6][o & 63] = v;
    }
    if (tid < 7) {
        float v = 0.f;
        #pragma unroll
        for (int c = 0; c < 16; ++c) v += Yb[c * 456 + 448 + tid];
        wsC[tid] = v;
    }
    __syncthreads();

    {
        float (*scr)[64] = wss[wv];
        #pragma unroll 1
        for (int sp = 0; sp < 2; ++sp) {
            const int s = wv + sp * 4;          // wv0:{0,4} wv1:{1,5} wv2:{2,6} wv3:{3}
            if (s >= 7) break;
            const int r = b * 7 + s;

            const float Yd = wsYd[s][lane];
            const float C  = wsC[s];
            const float Z  = wsum(Yd) * (1.0f / 64.0f);
            const float a  = (lig[lane] * (Yd - Z) + lib[lane] * C) / C;
            scr[0][lane] = a;
            float u = 0.f;
            #pragma unroll 8
            for (int i = 0; i < 64; ++i) u = fmaf(scr[0][i], Wv[i * 64 + lane], u);
            const float h = slots_rd[r * 64 + lane];
            scr[1][lane] = u;
            scr[2][lane] = h;

            float gi0 = bih[lane], gi1 = bih[64 + lane], gi2 = bih[128 + lane];
            float gh0 = bhh[lane], gh1 = bhh[64 + lane], gh2 = bhh[128 + lane];
            #pragma unroll 4
            for (int i = 0; i < 64; ++i) {
                const float ui = scr[1][i], hi = scr[2][i];
                const float* wi = &wihT[i * 192];
                const float* wh = &whhT[i * 192];
                gi0 = fmaf(ui, wi[lane], gi0);
                gi1 = fmaf(ui, wi[64 + lane], gi1);
                gi2 = fmaf(ui, wi[128 + lane], gi2);
                gh0 = fmaf(hi, wh[lane], gh0);
                gh1 = fmaf(hi, wh[64 + lane], gh1);
                gh2 = fmaf(hi, wh[128 + lane], gh2);
            }
            const float rr = sigm(gi0 + gh0);
            const float zz = sigm(gi1 + gh1);
            const float nn = tanh_(gi2 + rr * gh2);
            const float hn = (1.f - zz) * nn + zz * h;
            scr[0][lane] = hn;

            float m0 = b1[lane], m1 = b1[64 + lane];
            #pragma unroll 8
            for (int i = 0; i < 64; ++i) {
                const float hi = scr[0][i];
                m0 = fmaf(hi, w1[i * 128 + lane], m0);
                m1 = fmaf(hi, w1[i * 128 + 64 + lane], m1);
            }
            scr[1][lane] = fmaxf(m0, 0.f);
            scr[2][lane] = fmaxf(m1, 0.f);

            float o2 = b2[lane];
            #pragma unroll 8
            for (int t2 = 0; t2 < 64; ++t2)
                o2 = fmaf(scr[1][t2], w2[t2 * 64 + lane], o2);
            #pragma unroll 8
            for (int t2 = 0; t2 < 64; ++t2)
                o2 = fmaf(scr[2][t2], w2[(64 + t2) * 64 + lane], o2);
            const float snv = hn + o2;
            slots_wr[r * 64 + lane] = snv;      // 16 identical copies: benign

            const float mean = wsum(snv) * (1.0f / 64.0f);
            const float d = snv - mean;
            const float var = wsum(d * d) * (1.0f / 64.0f);
            const float rs = rsqrtf(var + 1e-5f);
            const float sn = d * rs * lsg[lane] + lsb[lane];
            scr[3][lane] = sn;
            float q = 0.f;
            #pragma unroll 8
            for (int i = 0; i < 64; ++i) q = fmaf(scr[3][i], Wq[i * 64 + lane], q);
            q *= 0.125f;
            scr[0][lane] = q;
            float kq = 0.f;
            #pragma unroll 8
            for (int p = 0; p < 64; ++p) kq = fmaf(WkT[p * 64 + lane], scr[0][p], kq);
            const float bk2 = wsum(lib[lane] * kq);
            const float gkv = lig[lane] * kq;
            const float g1v = wsum(gkv);
            gkql[s * 64 + lane] = gkv;
            if (lane == 0) { auxl[2 * s] = g1v; auxl[2 * s + 1] = bk2; }
        }
    }
    __syncthreads();

    // ---- attn phase (R1-verbatim flow; gk/aux from LDS, m/rs preloaded) ----
    float gk[7][8];
    #pragma unroll
    for (int s = 0; s < 7; ++s) {
        #pragma unroll
        for (int j = 0; j < 8; ++j) gk[s][j] = gkql[s * 64 + ck * 8 + j];
    }
    float g1[7], bk[7];
    #pragma unroll
    for (int s = 0; s < 7; ++s) { g1[s] = auxl[2 * s]; bk[s] = auxl[2 * s + 1]; }

    float Yacc[7][8];
    #pragma unroll
    for (int s = 0; s < 7; ++s)
        #pragma unroll
        for (int j = 0; j < 8; ++j) Yacc[s][j] = 0.f;
    float cacc[7] = {0.f, 0.f, 0.f, 0.f, 0.f, 0.f, 0.f};

    #pragma unroll 1
    for (int g = 0; g < 8; ++g) {
        const int gn = (g < 7) ? g + 1 : 7;
        const float4 n0 = *(const float4*)(rb + gn * 512);
        const float4 n1 = *(const float4*)(rb + gn * 512 + 4);
        const float2 stn = stats[(long)b * 4096 + rowbase + gn * 8];

        const float xv[8] = {a0.x, a0.y, a0.z, a0.w, a1.x, a1.y, a1.z, a1.w};
        float acc[7];
        #pragma unroll
        for (int s = 0; s < 7; ++s) {
            float a = 0.f;
            #pragma unroll
            for (int j = 0; j < 8; ++j) a = fmaf(xv[j], gk[s][j], a);
            acc[s] = a;
        }
        #pragma unroll
        for (int s = 0; s < 7; ++s) acc[s] = red8(acc[s]);

        const float m  = st.x;
        const float rs = st.y;
        const float rsm = rs * m;
        float t[7];
        #pragma unroll
        for (int s = 0; s < 7; ++s)
            t[s] = fmaf(rs, acc[s], fmaf(-rsm, g1[s], bk[s]));
        float mx = t[0];
        #pragma unroll
        for (int s = 1; s < 7; ++s) mx = fmaxf(mx, t[s]);
        float e[7], se = 0.f;
        #pragma unroll
        for (int s = 0; s < 7; ++s) {
            e[s] = __builtin_amdgcn_exp2f((t[s] - mx) * L2E);
            se += e[s];
        }
        const float inv = 1.0f / se;
        #pragma unroll
        for (int s = 0; s < 7; ++s) {
            const float w = fmaf(e[s], inv, 1e-8f);
            cacc[s] += w;
            const float wrs = w * rs;
            #pragma unroll
            for (int j = 0; j < 8; ++j)
                Yacc[s][j] = fmaf(wrs, xv[j], Yacc[s][j]);
        }
        a0 = n0; a1 = n1; st = stn;
    }

    #pragma unroll
    for (int s = 0; s < 7; ++s) {
        #pragma unroll
        for (int j = 0; j < 8; ++j)
            Yacc[s][j] += dppterm<0x128>(Yacc[s][j]);
        cacc[s] += dppterm<0x128>(cacc[s]);
    }
    if (((lane >> 3) & 1) == 0) {
        const int sub = lane >> 4;
        float* yb = &ybuf[wv * 4 + sub][ck * 8];
        #pragma unroll
        for (int s = 0; s < 7; ++s) {
            #pragma unroll
            for (int j = 0; j < 8; ++j) yb[s * 64 + j] = Yacc[s][j];
        }
        if (ck == 0) {
            #pragma unroll
            for (int s = 0; s < 7; ++s)
                ybuf[wv * 4 + sub][448 + s] = cacc[s];
        }
    }
    __syncthreads();
    for (int i = tid; i < 455; i += 256) {
        float v = 0.f;
        #pragma unroll
        for (int p = 0; p < 16; ++p) v += ybuf[p][i];
        Ycur[((long)b * 16 + chunk16) * 456 + i] = v;
    }
}

// ---------------------------------------------------------------------------
// update v3 (final iter only): ONE block (512 thr) per batch; writes out.
// grid 64 x 512. (R5-verbatim, last=1 path)
// ---------------------------------------------------------------------------
__global__ __launch_bounds__(512) void update_kernel(
    const float* __restrict__ Ypart, float* __restrict__ slots,
    const float* __restrict__ Wv,
    const float* __restrict__ wihT, const float* __restrict__ whhT,
    const float* __restrict__ bih,  const float* __restrict__ bhh,
    const float* __restrict__ w1,   const float* __restrict__ b1,
    const float* __restrict__ w2,   const float* __restrict__ b2,
    const float* __restrict__ lig,  const float* __restrict__ lib,
    float* __restrict__ out)
{
    __shared__ float wsYd[7][64];
    __shared__ float wsC[8];
    __shared__ float wss[7][4][64];
    const int tid = threadIdx.x, lane = tid & 63, wv = tid >> 6;
    const int b = blockIdx.x;
    const float* Yb = Ypart + (long)b * 16 * 456;

    if (tid < 448) {
        float v = 0.f;
        #pragma unroll
        for (int c = 0; c < 16; ++c) v += Yb[c * 456 + tid];
        wsYd[tid >> 6][tid & 63] = v;
    } else if (tid < 455) {
        const int s = tid - 448;
        float v = 0.f;
        #pragma unroll
        for (int c = 0; c < 16; ++c) v += Yb[c * 456 + 448 + s];
        wsC[s] = v;
    }
    __syncthreads();

    if (wv < 7) {
        const int s = wv;
        const int r = b * 7 + s;
        float (*scr)[64] = wss[wv];

        const float Yd = wsYd[s][lane];
        const float C  = wsC[s];
        const float Z  = wsum(Yd) * (1.0f / 64.0f);
        const float a  = (lig[lane] * (Yd - Z) + lib[lane] * C) / C;
        scr[0][lane] = a;
        float u = 0.f;
        #pragma unroll 8
        for (int i = 0; i < 64; ++i) u = fmaf(scr[0][i], Wv[i * 64 + lane], u);
        const float h = slots[r * 64 + lane];
        scr[1][lane] = u;
        scr[2][lane] = h;

        float gi0 = bih[lane], gi1 = bih[64 + lane], gi2 = bih[128 + lane];
        float gh0 = bhh[lane], gh1 = bhh[64 + lane], gh2 = bhh[128 + lane];
        #pragma unroll 4
        for (int i = 0; i < 64; ++i) {
            const float ui = scr[1][i], hi = scr[2][i];
            const float* wi = &wihT[i * 192];
            const float* wh = &whhT[i * 192];
            gi0 = fmaf(ui, wi[lane], gi0);
            gi1 = fmaf(ui, wi[64 + lane], gi1);
            gi2 = fmaf(ui, wi[128 + lane], gi2);
            gh0 = fmaf(hi, wh[lane], gh0);
            gh1 = fmaf(hi, wh[64 + lane], gh1);
            gh2 = fmaf(hi, wh[128 + lane], gh2);
        }
        const float rr = sigm(gi0 + gh0);
        const float zz = sigm(gi1 + gh1);
        const float nn = tanh_(gi2 + rr * gh2);
        const float hn = (1.f - zz) * nn + zz * h;
        scr[0][lane] = hn;

        float m0 = b1[lane], m1 = b1[64 + lane];
        #pragma unroll 8
        for (int i = 0; i < 64; ++i) {
            const float hi = scr[0][i];
            m0 = fmaf(hi, w1[i * 128 + lane], m0);
            m1 = fmaf(hi, w1[i * 128 + 64 + lane], m1);
        }
        scr[1][lane] = fmaxf(m0, 0.f);
        scr[2][lane] = fmaxf(m1, 0.f);

        float o2 = b2[lane];
        #pragma unroll 8
        for (int t = 0; t < 64; ++t)
            o2 = fmaf(scr[1][t], w2[t * 64 + lane], o2);
        #pragma unroll 8
        for (int t = 0; t < 64; ++t)
            o2 = fmaf(scr[2][t], w2[(64 + t) * 64 + lane], o2);
        out[r * 64 + lane] = hn + o2;
    }
}

// ---------------------------------------------------------------------------
extern "C" void kernel_launch(void* const* d_in, const int* in_sizes, int n_in,
                              void* d_out, int out_size, void* d_ws, size_t ws_size,
                              hipStream_t stream)
{
    const float* x   = (const float*)d_in[0];
    const float* lig = (const float*)d_in[1];
    const float* lib = (const float*)d_in[2];
    const float* lsg = (const float*)d_in[3];
    const float* lsb = (const float*)d_in[4];
    const float* s0  = (const float*)d_in[5];
    const float* Wk  = (const float*)d_in[6];
    const float* Wv  = (const float*)d_in[7];
    const float* Wq  = (const float*)d_in[8];
    const float* wih = (const float*)d_in[9];
    const float* whh = (const float*)d_in[10];
    const float* bih = (const float*)d_in[11];
    const float* bhh = (const float*)d_in[12];
    const float* w1  = (const float*)d_in[13];
    const float* b1  = (const float*)d_in[14];
    const float* w2  = (const float*)d_in[15];
    const float* b2  = (const float*)d_in[16];

    float* f = (float*)d_ws;
    float* gkq   = f; f += 448 * 64;
    float* aux   = f; f += 448 * 2;
    float* sl0   = f; f += 448 * 64;
    float* sl1   = f; f += 448 * 64;
    float* Yp0   = f; f += (long)64 * 16 * 456;
    float* Yp1   = f; f += (long)64 * 16 * 456;
    float* wihT  = f; f += 64 * 192;
    float* whhT  = f; f += 64 * 192;
    float* WkT   = f; f += 64 * 64;
    float2* stats = (float2*)f; f += (long)2 * 64 * 4096;

    init_kernel<<<112, 256, 0, stream>>>(s0, lsg, lsb, Wq, Wk, lig, lib,
                                         wih, whh, sl0, gkq, aux,
                                         wihT, whhT, WkT);
    // iter 0 attention (stores LN stats)
    attn_first<<<1024, 256, 0, stream>>>(x, gkq, aux, Yp0, stats);
    // iter 1: update0 (prologue) + attn1
    attn_fused<<<1024, 256, 0, stream>>>(x, stats, Yp0, Yp1, sl0, sl1,
                                         Wv, wihT, whhT, bih, bhh, w1, b1,
                                         w2, b2, lsg, lsb, Wq, WkT, lig, lib);
    // iter 2: update1 (prologue) + attn2
    attn_fused<<<1024, 256, 0, stream>>>(x, stats, Yp1, Yp0, sl1, sl0,
                                         Wv, wihT, whhT, bih, bhh, w1, b1,
                                         w2, b2, lsg, lsb, Wq, WkT, lig, lib);
    // final update2 -> out
    update_kernel<<<64, 512, 0, stream>>>(Yp0, sl0, Wv, wihT, whhT, bih, bhh,
                                          w1, b1, w2, b2, lig, lib,
                                          (float*)d_out);
}

// Round 8
// 226.202 us; speedup vs baseline: 1.3957x; 1.3957x over previous
//
#include <hip/hip_runtime.h>
#include <stdint.h>

#define L2E 1.44269504088896f

static __device__ __forceinline__ float wsum(float v) {
    #pragma unroll
    for (int m = 1; m < 64; m <<= 1) v += __shfl_xor(v, m, 64);
    return v;
}
static __device__ __forceinline__ float sigm(float x) {
    return 1.0f / (1.0f + __builtin_amdgcn_exp2f(-x * L2E));
}
static __device__ __forceinline__ float tanh_(float x) {
    const float ax = fabsf(x);
    const float t = __builtin_amdgcn_exp2f(-2.0f * ax * L2E);
    const float r = (1.0f - t) / (1.0f + t);
    return (x < 0.f) ? -r : r;
}

// DPP helper: returns neighbor's value per compile-time ctrl (VALU-rate).
template <int CTRL>
static __device__ __forceinline__ float dppterm(float v) {
    return __int_as_float(__builtin_amdgcn_update_dpp(
        0, __float_as_int(v), CTRL, 0xF, 0xF, true));
}
// Butterfly sum over 8 contiguous lanes (chunk = lane&7). All adds
// commutative -> bitwise-identical result in all 8 lanes.
static __device__ __forceinline__ float red8(float v) {
    v += dppterm<0xB1>(v);    // quad_perm(1,0,3,2)  = xor1
    v += dppterm<0x4E>(v);    // quad_perm(2,3,0,1)  = xor2
    v += dppterm<0x141>(v);   // row_half_mirror     = xor7 (quads merged)
    return v;
}

// ---------------------------------------------------------------------------
// init: fused weight transpose (wihT/whhT/WkT) + slot broadcast + iter-0
// gkq/aux. grid 112 x 256. (R1-verbatim)
// ---------------------------------------------------------------------------
__global__ __launch_bounds__(256) void init_kernel(
    const float* __restrict__ s0,
    const float* __restrict__ lsg, const float* __restrict__ lsb,
    const float* __restrict__ Wq,  const float* __restrict__ Wk,
    const float* __restrict__ lig, const float* __restrict__ lib,
    const float* __restrict__ wih, const float* __restrict__ whh,
    float* __restrict__ slots, float* __restrict__ gkq, float* __restrict__ aux,
    float* __restrict__ wihT, float* __restrict__ whhT, float* __restrict__ WkT)
{
    __shared__ float wkT[4096];
    __shared__ float scr[4][64];
    const int tid = threadIdx.x, lane = tid & 63, wv = tid >> 6;
    const int idx = blockIdx.x * 256 + tid;

    if (idx < 12288) {
        const int i = idx / 192, j = idx - i * 192;
        wihT[idx] = wih[j * 64 + i];
    } else if (idx < 24576) {
        const int o = idx - 12288;
        const int i = o / 192, j = o - i * 192;
        whhT[o] = whh[j * 64 + i];
    } else {
        const int o = idx - 24576;
        const int p = o >> 6, d = o & 63;
        WkT[o] = Wk[d * 64 + p];
    }

    const int r = blockIdx.x * 4 + wv;          // 0..447
    const int s = r % 7;
    #pragma unroll
    for (int i = tid; i < 4096; i += 256) {
        const int d = i >> 6, p = i & 63;
        wkT[p * 64 + d] = Wk[i];
    }
    const float h = s0[s * 64 + lane];
    slots[r * 64 + lane] = h;
    __syncthreads();

    const float mean = wsum(h) * (1.0f / 64.0f);
    const float d = h - mean;
    const float var = wsum(d * d) * (1.0f / 64.0f);
    const float rs = rsqrtf(var + 1e-5f);
    const float sn = d * rs * lsg[lane] + lsb[lane];
    scr[wv][lane] = sn;
    __syncthreads();
    float q = 0.f;
    #pragma unroll 8
    for (int i = 0; i < 64; ++i) q = fmaf(scr[wv][i], Wq[i * 64 + lane], q);
    q *= 0.125f;
    __syncthreads();
    scr[wv][lane] = q;
    __syncthreads();
    float kq = 0.f;
    #pragma unroll 8
    for (int p = 0; p < 64; ++p) kq = fmaf(wkT[p * 64 + lane], scr[wv][p], kq);
    const float bk = wsum(lib[lane] * kq);
    const float gk = lig[lane] * kq;
    const float g1 = wsum(gk);
    gkq[r * 64 + lane] = gk;
    if (lane == 0) { aux[r * 2] = g1; aux[r * 2 + 1] = bk; }
}

// ---------------------------------------------------------------------------
// attn v4 (MLP-deep): R1's math verbatim, but the 8-group loop is FULLY
// UNROLLED with 16 individually named float4s so all x loads can be hoisted
// and kept in flight (up to 256 B/lane vs R1's 64 B/lane). R7 counters
// showed attn is latency-bound at 485 GB/s (6% peak) with ~0.5 KB/CU
// outstanding vs ~22 KB needed -- this attacks exactly that.
// Per-group math, accumulation order, epilogue: bit-identical to R1.
// grid B*16 = 1024 x 256.
// ---------------------------------------------------------------------------
#define PROC(A0, A1)                                                         \
    do {                                                                     \
        const float xv[8] = {A0.x, A0.y, A0.z, A0.w, A1.x, A1.y, A1.z, A1.w};\
        float sum = 0.f, ss = 0.f;                                           \
        _Pragma("unroll")                                                    \
        for (int j = 0; j < 8; ++j) {                                        \
            sum += xv[j]; ss = fmaf(xv[j], xv[j], ss);                       \
        }                                                                    \
        float acc[7];                                                        \
        _Pragma("unroll")                                                    \
        for (int s = 0; s < 7; ++s) {                                        \
            float a = 0.f;                                                   \
            _Pragma("unroll")                                                \
            for (int j = 0; j < 8; ++j) a = fmaf(xv[j], gk[s][j], a);        \
            acc[s] = a;                                                      \
        }                                                                    \
        sum = red8(sum);                                                     \
        ss  = red8(ss);                                                      \
        _Pragma("unroll")                                                    \
        for (int s = 0; s < 7; ++s) acc[s] = red8(acc[s]);                   \
        const float m   = sum * (1.0f / 64.0f);                              \
        const float var = ss * (1.0f / 64.0f) - m * m;                       \
        const float rs  = rsqrtf(var + 1e-5f);                               \
        const float rsm = rs * m;                                            \
        float t[7];                                                          \
        _Pragma("unroll")                                                    \
        for (int s = 0; s < 7; ++s)                                          \
            t[s] = fmaf(rs, acc[s], fmaf(-rsm, g1[s], bk[s]));               \
        float mx = t[0];                                                     \
        _Pragma("unroll")                                                    \
        for (int s = 1; s < 7; ++s) mx = fmaxf(mx, t[s]);                    \
        float e[7], se = 0.f;                                                \
        _Pragma("unroll")                                                    \
        for (int s = 0; s < 7; ++s) {                                        \
            e[s] = __builtin_amdgcn_exp2f((t[s] - mx) * L2E);                \
            se += e[s];                                                      \
        }                                                                    \
        const float inv = 1.0f / se;                                         \
        _Pragma("unroll")                                                    \
        for (int s = 0; s < 7; ++s) {                                        \
            const float w = fmaf(e[s], inv, 1e-8f);                          \
            cacc[s] += w;                                                    \
            const float wrs = w * rs;                                        \
            _Pragma("unroll")                                                \
            for (int j = 0; j < 8; ++j)                                      \
                Yacc[s][j] = fmaf(wrs, xv[j], Yacc[s][j]);                   \
        }                                                                    \
    } while (0)

__global__ __launch_bounds__(256, 2) void attn_kernel(
    const float* __restrict__ x,
    const float* __restrict__ gkq, const float* __restrict__ aux,
    float* __restrict__ Ypart)
{
    __shared__ float ybuf[16][460];             // 29.4 KB
    const int tid = threadIdx.x, lane = tid & 63, wv = tid >> 6;
    const int b = blockIdx.x >> 4, chunk16 = blockIdx.x & 15;
    const int ck  = lane & 7;                   // dim-chunk 0..7
    const int rsl = lane >> 3;                  // row-slot 0..7

    // gk fragments -> registers (once)
    float gk[7][8];
    {
        const float4* gp = (const float4*)(gkq + b * 448 + ck * 8);
        #pragma unroll
        for (int s = 0; s < 7; ++s) {
            const float4 u0 = gp[s * 16], u1 = gp[s * 16 + 1];
            gk[s][0] = u0.x; gk[s][1] = u0.y; gk[s][2] = u0.z; gk[s][3] = u0.w;
            gk[s][4] = u1.x; gk[s][5] = u1.y; gk[s][6] = u1.z; gk[s][7] = u1.w;
        }
    }
    const float* ab = aux + b * 14;
    float g1[7], bk[7];
    #pragma unroll
    for (int s = 0; s < 7; ++s) { g1[s] = ab[2 * s]; bk[s] = ab[2 * s + 1]; }

    float Yacc[7][8];
    #pragma unroll
    for (int s = 0; s < 7; ++s)
        #pragma unroll
        for (int j = 0; j < 8; ++j) Yacc[s][j] = 0.f;
    float cacc[7] = {0.f, 0.f, 0.f, 0.f, 0.f, 0.f, 0.f};

    const float* rb = x + (((long)b * 4096) + chunk16 * 256 + wv * 64 + rsl) * 64
                        + ck * 8;
    // all 16 x loads as named values -- scheduler hoists them into flight
    const float4 x0a = *(const float4*)(rb);
    const float4 x0b = *(const float4*)(rb + 4);
    const float4 x1a = *(const float4*)(rb + 512);
    const float4 x1b = *(const float4*)(rb + 516);
    const float4 x2a = *(const float4*)(rb + 1024);
    const float4 x2b = *(const float4*)(rb + 1028);
    const float4 x3a = *(const float4*)(rb + 1536);
    const float4 x3b = *(const float4*)(rb + 1540);
    const float4 x4a = *(const float4*)(rb + 2048);
    const float4 x4b = *(const float4*)(rb + 2052);
    const float4 x5a = *(const float4*)(rb + 2560);
    const float4 x5b = *(const float4*)(rb + 2564);
    const float4 x6a = *(const float4*)(rb + 3072);
    const float4 x6b = *(const float4*)(rb + 3076);
    const float4 x7a = *(const float4*)(rb + 3584);
    const float4 x7b = *(const float4*)(rb + 3588);

    PROC(x0a, x0b);
    PROC(x1a, x1b);
    PROC(x2a, x2b);
    PROC(x3a, x3b);
    PROC(x4a, x4b);
    PROC(x5a, x5b);
    PROC(x6a, x6b);
    PROC(x7a, x7b);

    // pair rowslots via DPP xor8 (row_ror:8 within 16 == lane^8), VALU-rate
    #pragma unroll
    for (int s = 0; s < 7; ++s) {
        #pragma unroll
        for (int j = 0; j < 8; ++j)
            Yacc[s][j] += dppterm<0x128>(Yacc[s][j]);
        cacc[s] += dppterm<0x128>(cacc[s]);
    }
    // rowslots 0,2,4,6 hold the 4 sub-partials (16 rows each)
    if (((lane >> 3) & 1) == 0) {
        const int sub = lane >> 4;              // 0..3
        float* yb = &ybuf[wv * 4 + sub][ck * 8];
        #pragma unroll
        for (int s = 0; s < 7; ++s) {
            #pragma unroll
            for (int j = 0; j < 8; ++j) yb[s * 64 + j] = Yacc[s][j];
        }
        if (ck == 0) {
            #pragma unroll
            for (int s = 0; s < 7; ++s)
                ybuf[wv * 4 + sub][448 + s] = cacc[s];
        }
    }
    __syncthreads();
    for (int i = tid; i < 455; i += 256) {
        float v = 0.f;
        #pragma unroll
        for (int p = 0; p < 16; ++p) v += ybuf[p][i];
        Ypart[((long)b * 16 + chunk16) * 456 + i] = v;
    }
}

// ---------------------------------------------------------------------------
// update v2 (R1-verbatim): one block (256 thr) per (b,s) row. grid 448.
// ---------------------------------------------------------------------------
__global__ __launch_bounds__(256) void update_kernel(
    const float* __restrict__ Ypart, float* __restrict__ slots,
    const float* __restrict__ Wv,
    const float* __restrict__ wihT, const float* __restrict__ whhT,
    const float* __restrict__ bih,  const float* __restrict__ bhh,
    const float* __restrict__ w1,   const float* __restrict__ b1,
    const float* __restrict__ w2,   const float* __restrict__ b2,
    const float* __restrict__ lsg,  const float* __restrict__ lsb,
    const float* __restrict__ Wq,   const float* __restrict__ WkT,
    const float* __restrict__ lig,  const float* __restrict__ lib,
    float* __restrict__ gkq, float* __restrict__ aux,
    float* __restrict__ out, int last)
{
    __shared__ float red[4][64];
    __shared__ float c16[16];
    __shared__ float ash[64];
    __shared__ float ush[64];
    __shared__ float hsh[64];
    __shared__ float gish[192], ghsh[192];
    __shared__ float hnsh[64];
    __shared__ float mbsh[128];
    __shared__ float qsh[64];
    const int tid = threadIdx.x, lane = tid & 63, wv = tid >> 6;
    const int r = blockIdx.x;                   // 0..447
    const int b = r / 7, s = r - b * 7;
    const float* Yb = Ypart + (long)b * 16 * 456;

    // stage 1: Y partial sums (4 chunks per wave), colsum parts, h load
    float yp = 0.f;
    #pragma unroll
    for (int c = 0; c < 4; ++c)
        yp += Yb[(wv * 4 + c) * 456 + s * 64 + lane];
    red[wv][lane] = yp;
    if (tid < 16) c16[tid] = Yb[tid * 456 + 448 + s];
    if (tid >= 64 && tid < 128) hsh[tid - 64] = slots[r * 64 + (tid - 64)];
    __syncthreads();

    if (tid < 64) {                             // wave 0
        const float Yd = red[0][lane] + red[1][lane] + red[2][lane] + red[3][lane];
        float C = 0.f;
        #pragma unroll
        for (int c = 0; c < 16; ++c) C += c16[c];
        const float Z = wsum(Yd) * (1.0f / 64.0f);   // Z = sum_d Y / 64
        ash[lane] = (lig[lane] * (Yd - Z) + lib[lane] * C) / C;
    }
    __syncthreads();

    // stage 2: u = aoc @ Wv, i-split over 4 waves
    float up = 0.f;
    #pragma unroll
    for (int i = 0; i < 16; ++i) {
        const int ii = wv * 16 + i;
        up = fmaf(ash[ii], Wv[ii * 64 + lane], up);
    }
    red[wv][lane] = up;
    __syncthreads();
    if (tid < 64) ush[lane] = red[0][lane] + red[1][lane] + red[2][lane] + red[3][lane];
    __syncthreads();

    // stage 3: GRU gates (192 outputs, coalesced transposed weights)
    if (tid < 192) {
        float a1 = bih[tid], a2 = bhh[tid];
        #pragma unroll 8
        for (int i = 0; i < 64; ++i) {
            a1 = fmaf(ush[i], wihT[i * 192 + tid], a1);
            a2 = fmaf(hsh[i], whhT[i * 192 + tid], a2);
        }
        gish[tid] = a1; ghsh[tid] = a2;
    }
    __syncthreads();
    if (tid < 64) {
        const float rr = sigm(gish[tid] + ghsh[tid]);
        const float zz = sigm(gish[64 + tid] + ghsh[64 + tid]);
        const float nn = tanh_(gish[128 + tid] + rr * ghsh[128 + tid]);
        hnsh[tid] = (1.f - zz) * nn + zz * hsh[tid];
    }
    __syncthreads();

    // stage 4: MLP hidden (128 outputs)
    if (tid < 128) {
        float m = b1[tid];
        #pragma unroll 8
        for (int i = 0; i < 64; ++i) m = fmaf(hnsh[i], w1[i * 128 + tid], m);
        mbsh[tid] = fmaxf(m, 0.f);
    }
    __syncthreads();

    // stage 5: MLP out + residual; tail (wave 0 only, no barriers needed)
    if (tid < 64) {
        float o = b2[tid];
        #pragma unroll 8
        for (int t = 0; t < 128; ++t) o = fmaf(mbsh[t], w2[t * 64 + tid], o);
        const float snv = hnsh[tid] + o;
        slots[r * 64 + tid] = snv;
        if (last) {
            out[r * 64 + tid] = snv;
        } else {
            const float mean = wsum(snv) * (1.0f / 64.0f);
            const float d = snv - mean;
            const float var = wsum(d * d) * (1.0f / 64.0f);
            const float rs = rsqrtf(var + 1e-5f);
            const float sn = d * rs * lsg[tid] + lsb[tid];
            ash[tid] = sn;                       // wave0-internal reuse
            float q = 0.f;
            #pragma unroll 8
            for (int i = 0; i < 64; ++i) q = fmaf(ash[i], Wq[i * 64 + tid], q);
            qsh[tid] = q * 0.125f;
            float kq = 0.f;
            #pragma unroll 8
            for (int p = 0; p < 64; ++p) kq = fmaf(WkT[p * 64 + tid], qsh[p], kq);
            const float bk = wsum(lib[tid] * kq);
            const float gk = lig[tid] * kq;
            const float g1 = wsum(gk);
            gkq[r * 64 + tid] = gk;
            if (tid == 0) { aux[r * 2] = g1; aux[r * 2 + 1] = bk; }
        }
    }
}

// ---------------------------------------------------------------------------
extern "C" void kernel_launch(void* const* d_in, const int* in_sizes, int n_in,
                              void* d_out, int out_size, void* d_ws, size_t ws_size,
                              hipStream_t stream)
{
    const float* x   = (const float*)d_in[0];
    const float* lig = (const float*)d_in[1];
    const float* lib = (const float*)d_in[2];
    const float* lsg = (const float*)d_in[3];
    const float* lsb = (const float*)d_in[4];
    const float* s0  = (const float*)d_in[5];
    const float* Wk  = (const float*)d_in[6];
    const float* Wv  = (const float*)d_in[7];
    const float* Wq  = (const float*)d_in[8];
    const float* wih = (const float*)d_in[9];
    const float* whh = (const float*)d_in[10];
    const float* bih = (const float*)d_in[11];
    const float* bhh = (const float*)d_in[12];
    const float* w1  = (const float*)d_in[13];
    const float* b1  = (const float*)d_in[14];
    const float* w2  = (const float*)d_in[15];
    const float* b2  = (const float*)d_in[16];

    float* f = (float*)d_ws;
    float* gkq   = f; f += 448 * 64;
    float* aux   = f; f += 448 * 2;
    float* slots = f; f += 448 * 64;
    float* Ypart = f; f += (long)64 * 16 * 456;
    float* wihT  = f; f += 64 * 192;
    float* whhT  = f; f += 64 * 192;
    float* WkT   = f; f += 64 * 64;

    init_kernel<<<112, 256, 0, stream>>>(s0, lsg, lsb, Wq, Wk, lig, lib,
                                         wih, whh, slots, gkq, aux,
                                         wihT, whhT, WkT);
    for (int it = 0; it < 3; ++it) {
        attn_kernel<<<1024, 256, 0, stream>>>(x, gkq, aux, Ypart);
        update_kernel<<<448, 256, 0, stream>>>(
            Ypart, slots, Wv, wihT, whhT, bih, bhh, w1, b1, w2, b2,
            lsg, lsb, Wq, WkT, lig, lib, gkq, aux,
            (float*)d_out, it == 2);
    }
}

// Round 9
// 225.778 us; speedup vs baseline: 1.3983x; 1.0019x over previous
//
#include <hip/hip_runtime.h>
#include <stdint.h>

#define L2E 1.44269504088896f

static __device__ __forceinline__ float wsum(float v) {
    #pragma unroll
    for (int m = 1; m < 64; m <<= 1) v += __shfl_xor(v, m, 64);
    return v;
}
static __device__ __forceinline__ float sigm(float x) {
    return 1.0f / (1.0f + __builtin_amdgcn_exp2f(-x * L2E));
}
static __device__ __forceinline__ float tanh_(float x) {
    const float ax = fabsf(x);
    const float t = __builtin_amdgcn_exp2f(-2.0f * ax * L2E);
    const float r = (1.0f - t) / (1.0f + t);
    return (x < 0.f) ? -r : r;
}

// DPP helper: returns neighbor's value per compile-time ctrl (VALU-rate).
template <int CTRL>
static __device__ __forceinline__ float dppterm(float v) {
    return __int_as_float(__builtin_amdgcn_update_dpp(
        0, __float_as_int(v), CTRL, 0xF, 0xF, true));
}
// Butterfly sum over 8 contiguous lanes (chunk = lane&7). All adds
// commutative -> bitwise-identical result in all 8 lanes.
static __device__ __forceinline__ float red8(float v) {
    v += dppterm<0xB1>(v);    // quad_perm(1,0,3,2)  = xor1
    v += dppterm<0x4E>(v);    // quad_perm(2,3,0,1)  = xor2
    v += dppterm<0x141>(v);   // row_half_mirror     = xor7 (quads merged)
    return v;
}

// ---------------------------------------------------------------------------
// init: fused weight transpose (wihT/whhT/WkT) + slot broadcast + iter-0
// gkq/aux. grid 112 x 256. (R1-verbatim)
// ---------------------------------------------------------------------------
__global__ __launch_bounds__(256) void init_kernel(
    const float* __restrict__ s0,
    const float* __restrict__ lsg, const float* __restrict__ lsb,
    const float* __restrict__ Wq,  const float* __restrict__ Wk,
    const float* __restrict__ lig, const float* __restrict__ lib,
    const float* __restrict__ wih, const float* __restrict__ whh,
    float* __restrict__ slots, float* __restrict__ gkq, float* __restrict__ aux,
    float* __restrict__ wihT, float* __restrict__ whhT, float* __restrict__ WkT)
{
    __shared__ float wkT[4096];
    __shared__ float scr[4][64];
    const int tid = threadIdx.x, lane = tid & 63, wv = tid >> 6;
    const int idx = blockIdx.x * 256 + tid;

    if (idx < 12288) {
        const int i = idx / 192, j = idx - i * 192;
        wihT[idx] = wih[j * 64 + i];
    } else if (idx < 24576) {
        const int o = idx - 12288;
        const int i = o / 192, j = o - i * 192;
        whhT[o] = whh[j * 64 + i];
    } else {
        const int o = idx - 24576;
        const int p = o >> 6, d = o & 63;
        WkT[o] = Wk[d * 64 + p];
    }

    const int r = blockIdx.x * 4 + wv;          // 0..447
    const int s = r % 7;
    #pragma unroll
    for (int i = tid; i < 4096; i += 256) {
        const int d = i >> 6, p = i & 63;
        wkT[p * 64 + d] = Wk[i];
    }
    const float h = s0[s * 64 + lane];
    slots[r * 64 + lane] = h;
    __syncthreads();

    const float mean = wsum(h) * (1.0f / 64.0f);
    const float d = h - mean;
    const float var = wsum(d * d) * (1.0f / 64.0f);
    const float rs = rsqrtf(var + 1e-5f);
    const float sn = d * rs * lsg[lane] + lsb[lane];
    scr[wv][lane] = sn;
    __syncthreads();
    float q = 0.f;
    #pragma unroll 8
    for (int i = 0; i < 64; ++i) q = fmaf(scr[wv][i], Wq[i * 64 + lane], q);
    q *= 0.125f;
    __syncthreads();
    scr[wv][lane] = q;
    __syncthreads();
    float kq = 0.f;
    #pragma unroll 8
    for (int p = 0; p < 64; ++p) kq = fmaf(wkT[p * 64 + lane], scr[wv][p], kq);
    const float bk = wsum(lib[lane] * kq);
    const float gk = lig[lane] * kq;
    const float g1 = wsum(gk);
    gkq[r * 64 + lane] = gk;
    if (lane == 0) { aux[r * 2] = g1; aux[r * 2 + 1] = bk; }
}

// ---------------------------------------------------------------------------
// attn v5 (async-LDS pipeline): global_load_lds staging (no dest VGPRs,
// deep vmcnt queue) + double-buffered per-wave LDS x tiles + counted
// s_waitcnt vmcnt(2) (never 0 mid-loop) + sched_barrier (rule #18).
// Per-group math is R1-verbatim (bit-exact). Same-wave producer/consumer:
// no barriers in the main loop. LDS 45.8 KB/block -> 3 blocks/CU
// (12 waves, ~24 KB in flight/CU vs ~9 KB needed at HBM latency).
// grid B*16 = 1024 x 256.
// ---------------------------------------------------------------------------
#define PROC(A0, A1)                                                         \
    do {                                                                     \
        const float xv[8] = {A0.x, A0.y, A0.z, A0.w, A1.x, A1.y, A1.z, A1.w};\
        float sum = 0.f, ss = 0.f;                                           \
        _Pragma("unroll")                                                    \
        for (int j = 0; j < 8; ++j) {                                        \
            sum += xv[j]; ss = fmaf(xv[j], xv[j], ss);                       \
        }                                                                    \
        float acc[7];                                                        \
        _Pragma("unroll")                                                    \
        for (int s = 0; s < 7; ++s) {                                        \
            float a = 0.f;                                                   \
            _Pragma("unroll")                                                \
            for (int j = 0; j < 8; ++j) a = fmaf(xv[j], gk[s][j], a);        \
            acc[s] = a;                                                      \
        }                                                                    \
        sum = red8(sum);                                                     \
        ss  = red8(ss);                                                      \
        _Pragma("unroll")                                                    \
        for (int s = 0; s < 7; ++s) acc[s] = red8(acc[s]);                   \
        const float m   = sum * (1.0f / 64.0f);                              \
        const float var = ss * (1.0f / 64.0f) - m * m;                       \
        const float rs  = rsqrtf(var + 1e-5f);                               \
        const float rsm = rs * m;                                            \
        float t[7];                                                          \
        _Pragma("unroll")                                                    \
        for (int s = 0; s < 7; ++s)                                          \
            t[s] = fmaf(rs, acc[s], fmaf(-rsm, g1[s], bk[s]));               \
        float mx = t[0];                                                     \
        _Pragma("unroll")                                                    \
        for (int s = 1; s < 7; ++s) mx = fmaxf(mx, t[s]);                    \
        float e[7], se = 0.f;                                                \
        _Pragma("unroll")                                                    \
        for (int s = 0; s < 7; ++s) {                                        \
            e[s] = __builtin_amdgcn_exp2f((t[s] - mx) * L2E);                \
            se += e[s];                                                      \
        }                                                                    \
        const float inv = 1.0f / se;                                         \
        _Pragma("unroll")                                                    \
        for (int s = 0; s < 7; ++s) {                                        \
            const float w = fmaf(e[s], inv, 1e-8f);                          \
            cacc[s] += w;                                                    \
            const float wrs = w * rs;                                        \
            _Pragma("unroll")                                                \
            for (int j = 0; j < 8; ++j)                                      \
                Yacc[s][j] = fmaf(wrs, xv[j], Yacc[s][j]);                   \
        }                                                                    \
    } while (0)

// stage group G (8 rows = 2 KB/wave) into xbuf[wv][BUF]: two 1 KB
// global_load_lds_dwordx4 wave-instructions. LDS dest = uniform base +
// lane*16 (HW rule); global src carries the per-lane offset.
#define STAGE(G, BUF)                                                        \
    do {                                                                     \
        const char* gs_ = (const char*)xw + (G) * 2048 + lane * 16;          \
        char* ls_ = (char*)&xbuf[wv][BUF][0][0];                             \
        __builtin_amdgcn_global_load_lds(                                    \
            (const __attribute__((address_space(1))) unsigned int*)gs_,      \
            (__attribute__((address_space(3))) unsigned int*)ls_, 16, 0, 0); \
        __builtin_amdgcn_global_load_lds(                                    \
            (const __attribute__((address_space(1))) unsigned int*)(gs_ + 1024), \
            (__attribute__((address_space(3))) unsigned int*)(ls_ + 1024),   \
            16, 0, 0);                                                       \
    } while (0)

#define WAITV(N)                                                             \
    do {                                                                     \
        asm volatile("s_waitcnt vmcnt(" #N ")" ::: "memory");                \
        __builtin_amdgcn_sched_barrier(0);                                   \
    } while (0)

#define PROCL(BUF)                                                           \
    do {                                                                     \
        const float4 A0_ = *(const float4*)&xbuf[wv][BUF][rsl][ck * 8];      \
        const float4 A1_ = *(const float4*)&xbuf[wv][BUF][rsl][ck * 8 + 4];  \
        PROC(A0_, A1_);                                                      \
    } while (0)

__global__ __launch_bounds__(256, 2) void attn_kernel(
    const float* __restrict__ x,
    const float* __restrict__ gkq, const float* __restrict__ aux,
    float* __restrict__ Ypart)
{
    __shared__ float ybuf[16][460];             // 29.4 KB
    __shared__ float xbuf[4][2][8][64];         // 16 KB: wave x dbuf x 8r x 64d
    const int tid = threadIdx.x, lane = tid & 63, wv = tid >> 6;
    const int b = blockIdx.x >> 4, chunk16 = blockIdx.x & 15;
    const int ck  = lane & 7;                   // dim-chunk 0..7
    const int rsl = lane >> 3;                  // row-slot 0..7

    // gk fragments -> registers (once), R1-verbatim
    float gk[7][8];
    {
        const float4* gp = (const float4*)(gkq + b * 448 + ck * 8);
        #pragma unroll
        for (int s = 0; s < 7; ++s) {
            const float4 u0 = gp[s * 16], u1 = gp[s * 16 + 1];
            gk[s][0] = u0.x; gk[s][1] = u0.y; gk[s][2] = u0.z; gk[s][3] = u0.w;
            gk[s][4] = u1.x; gk[s][5] = u1.y; gk[s][6] = u1.z; gk[s][7] = u1.w;
        }
    }
    const float* ab = aux + b * 14;
    float g1[7], bk[7];
    #pragma unroll
    for (int s = 0; s < 7; ++s) { g1[s] = ab[2 * s]; bk[s] = ab[2 * s + 1]; }

    float Yacc[7][8];
    #pragma unroll
    for (int s = 0; s < 7; ++s)
        #pragma unroll
        for (int j = 0; j < 8; ++j) Yacc[s][j] = 0.f;
    float cacc[7] = {0.f, 0.f, 0.f, 0.f, 0.f, 0.f, 0.f};

    // per-wave global row base (64 rows, contiguous 16 KB)
    const float* xw = x + (((long)b * 4096) + chunk16 * 256 + wv * 64) * 64;

    // drain gk/aux loads so vmcnt counting below is exact
    asm volatile("s_waitcnt vmcnt(0)" ::: "memory");
    __builtin_amdgcn_sched_barrier(0);

    // software pipeline: stage G+1 while computing G; vmcnt(2) keeps the
    // in-flight group pending, guarantees the consumed group has landed.
    STAGE(0, 0);
    STAGE(1, 1); WAITV(2); PROCL(0);
    STAGE(2, 0); WAITV(2); PROCL(1);
    STAGE(3, 1); WAITV(2); PROCL(0);
    STAGE(4, 0); WAITV(2); PROCL(1);
    STAGE(5, 1); WAITV(2); PROCL(0);
    STAGE(6, 0); WAITV(2); PROCL(1);
    STAGE(7, 1); WAITV(2); PROCL(0);
                 WAITV(0); PROCL(1);

    // pair rowslots via DPP xor8; rowslots 0,2,4,6 hold 4 sub-partials
    #pragma unroll
    for (int s = 0; s < 7; ++s) {
        #pragma unroll
        for (int j = 0; j < 8; ++j)
            Yacc[s][j] += dppterm<0x128>(Yacc[s][j]);
        cacc[s] += dppterm<0x128>(cacc[s]);
    }
    if (((lane >> 3) & 1) == 0) {
        const int sub = lane >> 4;              // 0..3
        float* yb = &ybuf[wv * 4 + sub][ck * 8];
        #pragma unroll
        for (int s = 0; s < 7; ++s) {
            #pragma unroll
            for (int j = 0; j < 8; ++j) yb[s * 64 + j] = Yacc[s][j];
        }
        if (ck == 0) {
            #pragma unroll
            for (int s = 0; s < 7; ++s)
                ybuf[wv * 4 + sub][448 + s] = cacc[s];
        }
    }
    __syncthreads();
    for (int i = tid; i < 455; i += 256) {
        float v = 0.f;
        #pragma unroll
        for (int p = 0; p < 16; ++p) v += ybuf[p][i];
        Ypart[((long)b * 16 + chunk16) * 456 + i] = v;
    }
}

// ---------------------------------------------------------------------------
// update v2 (R1-verbatim): one block (256 thr) per (b,s) row. grid 448.
// ---------------------------------------------------------------------------
__global__ __launch_bounds__(256) void update_kernel(
    const float* __restrict__ Ypart, float* __restrict__ slots,
    const float* __restrict__ Wv,
    const float* __restrict__ wihT, const float* __restrict__ whhT,
    const float* __restrict__ bih,  const float* __restrict__ bhh,
    const float* __restrict__ w1,   const float* __restrict__ b1,
    const float* __restrict__ w2,   const float* __restrict__ b2,
    const float* __restrict__ lsg,  const float* __restrict__ lsb,
    const float* __restrict__ Wq,   const float* __restrict__ WkT,
    const float* __restrict__ lig,  const float* __restrict__ lib,
    float* __restrict__ gkq, float* __restrict__ aux,
    float* __restrict__ out, int last)
{
    __shared__ float red[4][64];
    __shared__ float c16[16];
    __shared__ float ash[64];
    __shared__ float ush[64];
    __shared__ float hsh[64];
    __shared__ float gish[192], ghsh[192];
    __shared__ float hnsh[64];
    __shared__ float mbsh[128];
    __shared__ float qsh[64];
    const int tid = threadIdx.x, lane = tid & 63, wv = tid >> 6;
    const int r = blockIdx.x;                   // 0..447
    const int b = r / 7, s = r - b * 7;
    const float* Yb = Ypart + (long)b * 16 * 456;

    // stage 1: Y partial sums (4 chunks per wave), colsum parts, h load
    float yp = 0.f;
    #pragma unroll
    for (int c = 0; c < 4; ++c)
        yp += Yb[(wv * 4 + c) * 456 + s * 64 + lane];
    red[wv][lane] = yp;
    if (tid < 16) c16[tid] = Yb[tid * 456 + 448 + s];
    if (tid >= 64 && tid < 128) hsh[tid - 64] = slots[r * 64 + (tid - 64)];
    __syncthreads();

    if (tid < 64) {                             // wave 0
        const float Yd = red[0][lane] + red[1][lane] + red[2][lane] + red[3][lane];
        float C = 0.f;
        #pragma unroll
        for (int c = 0; c < 16; ++c) C += c16[c];
        const float Z = wsum(Yd) * (1.0f / 64.0f);   // Z = sum_d Y / 64
        ash[lane] = (lig[lane] * (Yd - Z) + lib[lane] * C) / C;
    }
    __syncthreads();

    // stage 2: u = aoc @ Wv, i-split over 4 waves
    float up = 0.f;
    #pragma unroll
    for (int i = 0; i < 16; ++i) {
        const int ii = wv * 16 + i;
        up = fmaf(ash[ii], Wv[ii * 64 + lane], up);
    }
    red[wv][lane] = up;
    __syncthreads();
    if (tid < 64) ush[lane] = red[0][lane] + red[1][lane] + red[2][lane] + red[3][lane];
    __syncthreads();

    // stage 3: GRU gates (192 outputs, coalesced transposed weights)
    if (tid < 192) {
        float a1 = bih[tid], a2 = bhh[tid];
        #pragma unroll 8
        for (int i = 0; i < 64; ++i) {
            a1 = fmaf(ush[i], wihT[i * 192 + tid], a1);
            a2 = fmaf(hsh[i], whhT[i * 192 + tid], a2);
        }
        gish[tid] = a1; ghsh[tid] = a2;
    }
    __syncthreads();
    if (tid < 64) {
        const float rr = sigm(gish[tid] + ghsh[tid]);
        const float zz = sigm(gish[64 + tid] + ghsh[64 + tid]);
        const float nn = tanh_(gish[128 + tid] + rr * ghsh[128 + tid]);
        hnsh[tid] = (1.f - zz) * nn + zz * hsh[tid];
    }
    __syncthreads();

    // stage 4: MLP hidden (128 outputs)
    if (tid < 128) {
        float m = b1[tid];
        #pragma unroll 8
        for (int i = 0; i < 64; ++i) m = fmaf(hnsh[i], w1[i * 128 + tid], m);
        mbsh[tid] = fmaxf(m, 0.f);
    }
    __syncthreads();

    // stage 5: MLP out + residual; tail (wave 0 only, no barriers needed)
    if (tid < 64) {
        float o = b2[tid];
        #pragma unroll 8
        for (int t = 0; t < 128; ++t) o = fmaf(mbsh[t], w2[t * 64 + tid], o);
        const float snv = hnsh[tid] + o;
        slots[r * 64 + tid] = snv;
        if (last) {
            out[r * 64 + tid] = snv;
        } else {
            const float mean = wsum(snv) * (1.0f / 64.0f);
            const float d = snv - mean;
            const float var = wsum(d * d) * (1.0f / 64.0f);
            const float rs = rsqrtf(var + 1e-5f);
            const float sn = d * rs * lsg[tid] + lsb[tid];
            ash[tid] = sn;                       // wave0-internal reuse
            float q = 0.f;
            #pragma unroll 8
            for (int i = 0; i < 64; ++i) q = fmaf(ash[i], Wq[i * 64 + tid], q);
            qsh[tid] = q * 0.125f;
            float kq = 0.f;
            #pragma unroll 8
            for (int p = 0; p < 64; ++p) kq = fmaf(WkT[p * 64 + tid], qsh[p], kq);
            const float bk = wsum(lib[tid] * kq);
            const float gk = lig[tid] * kq;
            const float g1 = wsum(gk);
            gkq[r * 64 + tid] = gk;
            if (tid == 0) { aux[r * 2] = g1; aux[r * 2 + 1] = bk; }
        }
    }
}

// ---------------------------------------------------------------------------
extern "C" void kernel_launch(void* const* d_in, const int* in_sizes, int n_in,
                              void* d_out, int out_size, void* d_ws, size_t ws_size,
                              hipStream_t stream)
{
    const float* x   = (const float*)d_in[0];
    const float* lig = (const float*)d_in[1];
    const float* lib = (const float*)d_in[2];
    const float* lsg = (const float*)d_in[3];
    const float* lsb = (const float*)d_in[4];
    const float* s0  = (const float*)d_in[5];
    const float* Wk  = (const float*)d_in[6];
    const float* Wv  = (const float*)d_in[7];
    const float* Wq  = (const float*)d_in[8];
    const float* wih = (const float*)d_in[9];
    const float* whh = (const float*)d_in[10];
    const float* bih = (const float*)d_in[11];
    const float* bhh = (const float*)d_in[12];
    const float* w1  = (const float*)d_in[13];
    const float* b1  = (const float*)d_in[14];
    const float* w2  = (const float*)d_in[15];
    const float* b2  = (const float*)d_in[16];

    float* f = (float*)d_ws;
    float* gkq   = f; f += 448 * 64;
    float* aux   = f; f += 448 * 2;
    float* slots = f; f += 448 * 64;
    float* Ypart = f; f += (long)64 * 16 * 456;
    float* wihT  = f; f += 64 * 192;
    float* whhT  = f; f += 64 * 192;
    float* WkT   = f; f += 64 * 64;

    init_kernel<<<112, 256, 0, stream>>>(s0, lsg, lsb, Wq, Wk, lig, lib,
                                         wih, whh, slots, gkq, aux,
                                         wihT, whhT, WkT);
    for (int it = 0; it < 3; ++it) {
        attn_kernel<<<1024, 256, 0, stream>>>(x, gkq, aux, Ypart);
        update_kernel<<<448, 256, 0, stream>>>(
            Ypart, slots, Wv, wihT, whhT, bih, bhh, w1, b1, w2, b2,
            lsg, lsb, Wq, WkT, lig, lib, gkq, aux,
            (float*)d_out, it == 2);
    }
}